// Round 4
// baseline (950.796 us; speedup 1.0000x reference)
//
#include <hip/hip_runtime.h>

#define GN 64
#define N_TOTAL (GN * GN * GN)   // 262144
#define KOFF 24

typedef float f4 __attribute__((ext_vector_type(4)));

// 24 Manhattan-radius-2 offsets, sorted by linear delta (dx*4096 + dy*64 + dz)
// ascending. List is symmetric under negation: inv(k) = 23 - k.
__device__ constexpr int DLc[KOFF] = {
    -8192, -4160, -4097, -4096, -4095, -4032,
     -128,   -65,   -64,   -63,    -2,    -1,
        1,     2,    63,    64,    65,   128,
     4032,  4095,  4096,  4097,  4160,  8192};
__device__ constexpr int DXc[KOFF] = {
    -2, -1, -1, -1, -1, -1, 0, 0, 0, 0, 0, 0,
     0,  0,  0,  0,  0,  0, 1, 1, 1, 1, 1, 2};
__device__ constexpr int DYc[KOFF] = {
     0, -1,  0,  0,  0,  1, -2, -1, -1, -1, 0, 0,
     0,  0,  1,  1,  1,  2, -1,  0,  0,  0, 1, 0};
__device__ constexpr int DZc[KOFF] = {
     0,  0, -1,  0,  1,  0,  0, -1,  0,  1, -2, -1,
     1,  2, -1,  0,  1,  0,  0, -1,  0,  1,  0,  0};

// Deterministic re-pack of ev into INCOMING plane-major layout:
//   wIn[k*N + j] = weight of edge (j+DL[k] -> j)   (0 if that edge invalid).
// Edges are lexsorted (row asc, col asc); row j's edges start at closed-form
// S(j) and appear in DL-ascending order. Thread j writes its OUTGOING edges
// to wIn[(23-k)*N + j+DL[k]] (lane-consecutive -> coalesced) and zeroes its
// own invalid incoming slots. Every slot written exactly once, no memset.
__global__ __launch_bounds__(256) void pack_w_kernel(
    const float* __restrict__ ev, float* __restrict__ w) {
    int j = blockIdx.x * 256 + threadIdx.x;
    int z = j & 63, y = (j >> 6) & 63, x = j >> 12;

    int S = 0;
#pragma unroll
    for (int k = 0; k < KOFF; k++) {
        int dx = DXc[k], dy = DYc[k], dz = DZc[k];
        int x0 = max(0, -dx), x1 = min(64, 64 - dx);
        int y0 = max(0, -dy), y1 = min(64, 64 - dy);
        int z0 = max(0, -dz), z1 = min(64, 64 - dz);
        int ny = y1 - y0, nz = z1 - z0;
        int nxb = max(0, min(x, x1) - x0);
        int cnt = nxb * ny * nz;
        if (x >= x0 && x < x1) {
            cnt += max(0, min(y, y1) - y0) * nz;
            if (y >= y0 && y < y1)
                cnt += max(0, min(z, z1) - z0);
        }
        S += cnt;
    }

    int idx = 0;
#pragma unroll
    for (int k = 0; k < KOFF; k++) {
        int nx = x + DXc[k], ny = y + DYc[k], nz = z + DZc[k];
        bool ok = ((unsigned)nx < 64u) & ((unsigned)ny < 64u) &
                  ((unsigned)nz < 64u);
        if (ok) {
            w[(23 - k) * N_TOTAL + (j + DLc[k])] = ev[S + idx];
            idx++;
        } else {
            w[k * N_TOTAL + j] = 0.0f;
        }
    }
}

// Fused step with one-step-lagged STDP. MODE 0: t==0 (no gather, v=REST).
// MODE 1: t==1 (gather with w as stored, no update). MODE 2: t>=2 (read
// w_{t-2}, reconstruct w_{t-1} on the fly using pre=prev2[j] (scalar),
// post=prev[nb] (the gathered value), use for syn, write back).
// Each thread handles 4 consecutive neurons; all w accesses aligned float4.
template <int MODE>
__global__ __launch_bounds__(256) void step_kernel(
    const float* __restrict__ xext,      // external_input + t*N (read-once)
    const float* __restrict__ w_old,     // w_{t-2} (MODE2) / w_0 (MODE1)
    float* __restrict__ w_new,           // w_{t-1} written (MODE2 only)
    const float* __restrict__ prev,      // out_{t-1}
    const float* __restrict__ prev2,     // out_{t-2} (MODE2 only)
    float* __restrict__ out,             // out_t
    float* __restrict__ v,
    float* __restrict__ spk) {           // d_out + t*N (write-only)
#pragma clang fp contract(off)
    int j0 = (blockIdx.x * 256 + threadIdx.x) * 4;
    int z0 = j0 & 63, y = (j0 >> 6) & 63, x = j0 >> 12;

    float syn[4] = {0.0f, 0.0f, 0.0f, 0.0f};
    float pre2[4];
    if (MODE == 2) {
        f4 q = *(const f4*)(prev2 + j0);
        pre2[0] = q.x; pre2[1] = q.y; pre2[2] = q.z; pre2[3] = q.w;
    }

    if (MODE >= 1) {
#pragma unroll
        for (int k = 0; k < KOFF; k++) {
            int nx = x + DXc[k], nyy = y + DYc[k];
            bool okxy = ((unsigned)nx < 64u) & ((unsigned)nyy < 64u);
            int nzb = z0 + DZc[k];                 // nz for elem i = nzb + i
            f4 wq = *(const f4*)(w_old + k * N_TOTAL + j0);
            float wv[4] = {wq.x, wq.y, wq.z, wq.w};
            float nw[4];
#pragma unroll
            for (int i = 0; i < 4; i++) {
                bool ok = okxy & ((unsigned)(nzb + i) < 64u);
                float p = ok ? prev[j0 + i + DLc[k]] : 0.0f;
                float nwi;
                if (MODE == 2) {
                    float a = (0.01f * pre2[i]) * p;
                    float b = (0.005f * pre2[i]) * (1.0f - p);
                    float c = 1e-5f * wv[i];
                    float dw = (a - b) - c;
                    float cl = fminf(fmaxf(wv[i] + dw, 0.0f), 1.0f);
                    nwi = ok ? cl : 0.0f;
                } else {
                    nwi = wv[i];
                }
                nw[i] = nwi;
                float m = nwi * p;   // contract(off): mul then add, like numpy
                syn[i] = syn[i] + m; // k-ascending == segment_sum order
            }
            if (MODE == 2) {
                f4 s; s.x = nw[0]; s.y = nw[1]; s.z = nw[2]; s.w = nw[3];
                *(f4*)(w_new + k * N_TOTAL + j0) = s;
            }
        }
    }

    const float decay = expf(-1.0f / 20.0f);
    f4 xq;
    xq.x = __builtin_nontemporal_load(xext + j0 + 0);
    xq.y = __builtin_nontemporal_load(xext + j0 + 1);
    xq.z = __builtin_nontemporal_load(xext + j0 + 2);
    xq.w = __builtin_nontemporal_load(xext + j0 + 3);
    f4 vq;
    if (MODE >= 1) vq = *(const f4*)(v + j0);

    f4 vo, oo, so;
    float xv[4] = {xq.x, xq.y, xq.z, xq.w};
    float vv[4] = {vq.x, vq.y, vq.z, vq.w};
    float vr[4], orr[4], sr[4];
#pragma unroll
    for (int i = 0; i < 4; i++) {
        float myv = (MODE == 0) ? -65.0f : vv[i];
        float I = syn[i] + xv[i];
        float vn = (myv * decay) + (I * (1.0f - decay));
        float spike = (vn >= -50.0f) ? 1.0f : 0.0f;
        float inhib = (vn <= -70.0f) ? 1.0f : 0.0f;
        float sg = 1.0f / (1.0f + expf(-((vn - (-60.0f)) * 0.5f)));
        float o = spike + ((1.0f - spike) * (1.0f - inhib)) * sg;
        vr[i] = (vn * (1.0f - spike)) + (spike * (-65.0f));
        orr[i] = o;
        sr[i] = spike;
    }
    vo.x = vr[0]; vo.y = vr[1]; vo.z = vr[2]; vo.w = vr[3];
    oo.x = orr[0]; oo.y = orr[1]; oo.z = orr[2]; oo.w = orr[3];
    so.x = sr[0]; so.y = sr[1]; so.z = sr[2]; so.w = sr[3];
    *(f4*)(v + j0) = vo;
    *(f4*)(out + j0) = oo;
    __builtin_nontemporal_store(so, (f4*)(spk + j0));
}

extern "C" void kernel_launch(void* const* d_in, const int* in_sizes, int n_in,
                              void* d_out, int out_size, void* d_ws, size_t ws_size,
                              hipStream_t stream) {
    const float* xext = (const float*)d_in[0];
    const float* ev   = (const float*)d_in[1];
    float* spk = (float*)d_out;

    int T = in_sizes[0] / N_TOTAL;   // 50

    // Workspace: W0 | W1 | P0 | P1 | P2 | v  -> (48 + 4) * N floats ≈ 54.5 MB
    float* W[2];
    W[0] = (float*)d_ws;
    W[1] = W[0] + (size_t)N_TOTAL * KOFF;
    float* P[3];
    P[0] = W[1] + (size_t)N_TOTAL * KOFF;
    P[1] = P[0] + N_TOTAL;
    P[2] = P[1] + N_TOTAL;
    float* vb = P[2] + N_TOTAL;

    pack_w_kernel<<<N_TOTAL / 256, 256, 0, stream>>>(ev, W[0]);

    const int NB = N_TOTAL / 4 / 256;   // 256 blocks
    for (int t = 0; t < T; t++) {
        float* po  = P[t % 3];
        float* pr  = P[(t + 2) % 3];   // (t-1) mod 3
        float* pr2 = P[(t + 1) % 3];   // (t-2) mod 3
        const float* xt = xext + (size_t)t * N_TOTAL;
        float* st = spk + (size_t)t * N_TOTAL;
        if (t == 0) {
            step_kernel<0><<<NB, 256, 0, stream>>>(xt, W[0], W[1], pr, pr2,
                                                   po, vb, st);
        } else if (t == 1) {
            step_kernel<1><<<NB, 256, 0, stream>>>(xt, W[0], W[1], pr, pr2,
                                                   po, vb, st);
        } else {
            step_kernel<2><<<NB, 256, 0, stream>>>(xt, W[t & 1], W[(t + 1) & 1],
                                                   pr, pr2, po, vb, st);
        }
    }
}